// Round 1
// 17265.009 us; speedup vs baseline: 5.2458x; 5.2458x over previous
//
#include <hip/hip_runtime.h>

// Autoregressive GRU decoder, persistent cooperative kernel.
// B=128, S=512, HID=1024, EMB=128, NL=32.
//
// Input dtype (fp32 vs bf16) detected on-device; OUTPUT FORMAT IS COUPLED
// to the detected input dtype (f32 -> float out, bf16 -> u16 bf16 out).
//
// Numerics (fp32 mode): W = Whi(bf16,LDS) + Wlo(bf16, device-global,
// precomputed); x and h split hi/lo bf16 in-register. All 4 limb products
// go through bf16 MFMA into one fp32 accumulator -> gate preactivations
// accurate to ~1.5e-6. G_lab in fp64. Logits from exact fp32 h.
//
// COHERENCE SCHEME (this revision): no __threadfence / no L2 wbl2+inv.
// All mutable cross-WG data (h limbs, h fp32, GIX, pred, vis) is accessed
// through RELAXED agent-scope atomics (sc0|sc1 -> LLC write-through /
// cache-bypass reads). Barriers: __syncthreads drains each wave's vmem
// (compiler-inserted vmcnt(0) before s_barrier), arrival lane waits
// vmcnt(0) then does RELAXED atomic adds; spin is RELAXED (no buffer_inv
// per poll). Read-only data (weights, hs, Wlo limbs, Glab, W_out) stays
// L2-resident across steps. Sentinels 999/555 self-test visibility.

#define S_    512
#define HID_  1024
#define EMB_  128
#define NL_   32
#define G3_   3072

#define LDS_A_STRIDE 1032                      // 1024 + 8 pad (bf16 elems)
#define LDS_A_BYTES  (48 * LDS_A_STRIDE * 2)   // 99072
#define CP_STRIDE    52                        // fp32 elems, pad 48->52
#define LDS_CP_BYTES (4 * 64 * CP_STRIDE * 4)  // 53248
#define LDS_BYTES    (LDS_A_BYTES + LDS_CP_BYTES) // 152320 <= 160KiB

typedef __attribute__((ext_vector_type(8))) short          short8;
typedef __attribute__((ext_vector_type(8))) unsigned short u16x8;
typedef __attribute__((ext_vector_type(4))) unsigned short u16x4;
typedef __attribute__((ext_vector_type(4))) float          f32x4;
typedef unsigned long long u64_t;

// ---------------- device-global state (no d_ws dependence) ---------------
__device__ unsigned int   g_ctr[576];           // 8 groups @ +g*64, root @ +512
__device__ unsigned int   g_flag[1];
__device__ unsigned int   g_vis[256];
__device__ int            g_pred[128];
__device__ unsigned short g_hhi[128 * HID_];
__device__ unsigned short g_hlo[128 * HID_];
__device__ float          g_hf32[128 * HID_];
__device__ float          g_Glab[NL_ * G3_];    // b_ih folded in
__device__ float          g_GIX[128 * 64 * 48]; // [slot][bl][48]
__device__ unsigned short g_Wlox[G3_ * HID_];   // lo limb of W_ih x-part
__device__ unsigned short g_Wlohh[G3_ * HID_];  // lo limb of W_hh

__device__ __forceinline__ float bf2f(unsigned short u) {
  union { unsigned int i; float f; } v; v.i = ((unsigned int)u) << 16; return v.f;
}
__device__ __forceinline__ unsigned short f2bf(float f) {
  union { float f; unsigned int i; } v; v.f = f;
  unsigned int u = v.i;
  return (unsigned short)((u + 0x7FFFu + ((u >> 16) & 1u)) >> 16);
}
__device__ __forceinline__ short8 ld_bf8(const unsigned short* p) {
  return __builtin_bit_cast(short8, *(const u16x8*)p);
}
__device__ __forceinline__ float ldin(const void* p, long i, int f32) {
  return f32 ? ((const float*)p)[i] : bf2f(((const unsigned short*)p)[i]);
}
__device__ __forceinline__ void store_out(void* out, int f32, long idx, float v) {
  if (f32) ((float*)out)[idx] = v;
  else     ((unsigned short*)out)[idx] = f2bf(v);
}

// ---- coherent (LLC-level) access helpers: relaxed agent atomics -> sc0|sc1,
// no cache maintenance instructions, compiler-tracked vmcnt.
__device__ __forceinline__ u64_t ald64(const void* p) {
  return __hip_atomic_load((const u64_t*)p, __ATOMIC_RELAXED,
                           __HIP_MEMORY_SCOPE_AGENT);
}
__device__ __forceinline__ void ast64(void* p, u64_t v) {
  __hip_atomic_store((u64_t*)p, v, __ATOMIC_RELAXED,
                     __HIP_MEMORY_SCOPE_AGENT);
}
__device__ __forceinline__ unsigned int ald32(const unsigned int* p) {
  return __hip_atomic_load(p, __ATOMIC_RELAXED, __HIP_MEMORY_SCOPE_AGENT);
}
__device__ __forceinline__ void ast32(unsigned int* p, unsigned int v) {
  __hip_atomic_store(p, v, __ATOMIC_RELAXED, __HIP_MEMORY_SCOPE_AGENT);
}
__device__ __forceinline__ int aldi(const int* p) {
  return __hip_atomic_load(p, __ATOMIC_RELAXED, __HIP_MEMORY_SCOPE_AGENT);
}
__device__ __forceinline__ void asti(int* p, int v) {
  __hip_atomic_store(p, v, __ATOMIC_RELAXED, __HIP_MEMORY_SCOPE_AGENT);
}
__device__ __forceinline__ short8 ld_bf8_coh(const unsigned short* p) {
  union { u64_t q[2]; short8 s; } u;
  u.q[0] = ald64(p);
  u.q[1] = ald64(p + 4);
  return u.s;
}
__device__ __forceinline__ f32x4 ld_f4_coh(const float* p) {
  union { u64_t q[2]; f32x4 f; } u;
  u.q[0] = ald64(p);
  u.q[1] = ald64(p + 2);
  return u.f;
}
__device__ __forceinline__ void st_f4_coh(float* p, f32x4 v) {
  union { f32x4 f; u64_t q[2]; } u; u.f = v;
  ast64(p, u.q[0]);
  ast64(p + 2, u.q[1]);
}
__device__ __forceinline__ void st_h4_coh(unsigned short* p, u16x4 v) {
  union { u16x4 h; u64_t q; } u; u.h = v;
  ast64(p, u.q);
}

// ---- zero state each launch ----
__global__ void k_zero() {
  int t = blockIdx.x * 256 + threadIdx.x;       // 65536 threads
  if (t < 576) g_ctr[t] = 0u;
  else if (t < 832) g_vis[t - 576] = 0u;
  else if (t < 960) g_pred[t - 832] = 0;
  const u16x4 z4 = {0, 0, 0, 0};
  const f32x4 zf = {0.f, 0.f, 0.f, 0.f};
  for (int i = t; i < 128 * HID_ / 4; i += 65536) {
    ((u16x4*)g_hhi)[i] = z4;
    ((u16x4*)g_hlo)[i] = z4;
    ((f32x4*)g_hf32)[i] = zf;
  }
}

// ---- dtype detector: bf16 W_ih bounded by 1/32; fp32 misread blows up ----
__global__ void k_detect(const unsigned short* __restrict__ W) {
  unsigned bad = 0;
  for (int i = threadIdx.x; i < 1024; i += 64) {
    float v = bf2f(W[i]);
    if (!(v * v <= 1.0f)) bad = 1;   // catches |v|>1 and NaN
  }
  unsigned long long b = __ballot(bad != 0);
  if (threadIdx.x == 0) g_flag[0] = (b != 0ull) ? 1u : 0u;
}

// ---- prep: G_lab[l][n] = b_ih[n] + sum_e emb[l][e]*W_ih[n][1024+e] (fp64) --
__global__ void k_prep(const void* __restrict__ emb,
                       const void* __restrict__ W_ih,
                       const void* __restrict__ b_ih) {
  const int f32 = (int)g_flag[0];
  int l = blockIdx.x / 12;
  int n = (blockIdx.x % 12) * 256 + threadIdx.x;
  double acc = (double)ldin(b_ih, n, f32);
  for (int e = 0; e < EMB_; ++e)
    acc += (double)ldin(emb, (long)l * EMB_ + e, f32) *
           (double)ldin(W_ih, (long)n * (HID_ + EMB_) + HID_ + e, f32);
  g_Glab[l * G3_ + n] = (float)acc;
}

// ---- prep: lo limbs of W (fp32 mode only) ----
__global__ void k_prepw(const void* __restrict__ W_ih,
                        const void* __restrict__ W_hh) {
  if (!g_flag[0]) return;
  long i4 = ((long)blockIdx.x * 256 + threadIdx.x) * 4;  // 3072 blocks
  if (i4 >= (long)G3_ * HID_) return;
  int row = (int)(i4 >> 10), col = (int)(i4 & 1023);
  f32x4 wh = *(const f32x4*)&((const float*)W_hh)[(long)row * HID_ + col];
  f32x4 wx = *(const f32x4*)&((const float*)W_ih)[(long)row * (HID_ + EMB_) + col];
  u16x4 lh, lx;
  #pragma unroll
  for (int j = 0; j < 4; ++j) {
    unsigned short h1 = f2bf(wh[j]);
    lh[j] = f2bf(wh[j] - bf2f(h1));
    unsigned short x1 = f2bf(wx[j]);
    lx[j] = f2bf(wx[j] - bf2f(x1));
  }
  *(u16x4*)&g_Wlohh[i4] = lh;
  *(u16x4*)&g_Wlox[i4]  = lx;
}

// ---- 2-level device barrier: RELAXED atomics, no cache maintenance. ----
// Release: __syncthreads drains each wave's vmem (compiler emits
// s_waitcnt vmcnt(0) before s_barrier); arriving lane re-asserts vmcnt(0).
// All cross-WG payloads use sc0|sc1 atomics, so LLC arrival order of
// (data ... counter-add) gives the required happens-before without any
// buffer_wbl2 / buffer_inv. Acquire: readers bypass caches (sc0|sc1).
__device__ __forceinline__ void gridbar(int wg, int bar) {
  __syncthreads();
  if (threadIdx.x == 0) {
    asm volatile("s_waitcnt vmcnt(0)" ::: "memory");
    unsigned int* c1   = g_ctr + (wg & 7) * 64;
    unsigned int* root = g_ctr + 512;
    unsigned int old = __hip_atomic_fetch_add(c1, 1u, __ATOMIC_RELAXED,
                                              __HIP_MEMORY_SCOPE_AGENT);
    if (old == 32u * (unsigned)(bar + 1) - 1u)
      __hip_atomic_fetch_add(root, 1u, __ATOMIC_RELAXED,
                             __HIP_MEMORY_SCOPE_AGENT);
    unsigned int tgt = 8u * (unsigned)(bar + 1);
    while (__hip_atomic_load(root, __ATOMIC_RELAXED,
                             __HIP_MEMORY_SCOPE_AGENT) < tgt)
      __builtin_amdgcn_s_sleep(1);
  }
  __syncthreads();
}

// ---- main persistent kernel ----
__global__ __launch_bounds__(256) void k_seq(
    const void* __restrict__ hs,
    const void* __restrict__ W_ih,
    const void* __restrict__ W_hh,
    const void* __restrict__ b_hh,
    const void* __restrict__ W_out,
    const void* __restrict__ b_out,
    void* __restrict__ out) {
  extern __shared__ char smem[];
  unsigned short* sA  = (unsigned short*)smem;
  float*          sCp = (float*)(smem + LDS_A_BYTES);

  const int f32 = (int)g_flag[0];
  const int tid = threadIdx.x;
  const int wg  = blockIdx.x;
  const bool isx = (wg < 128);
  const int lid  = isx ? wg : wg - 128;
  const int rg = lid >> 1, bg = lid & 1;
  const int slot = lid;                 // shared (rg,bg) slot with partner WG
  const int lane = tid & 63, wv = tid >> 6;
  const int m = lane & 15, q = lane >> 4;
  const int bl = tid & 63;              // epilogue local batch
  const int jj = (tid >> 6) * 4;        // epilogue local j base

  // Stage hi-limb weight slice into LDS: rows [r16][z16][n16] of group rg.
  {
    const void* Wsrc = isx ? W_ih : W_hh;
    const int wstride = isx ? (HID_ + EMB_) : HID_;
    if (f32) {
      const float* Ws = (const float*)Wsrc;
      for (int i = tid; i < 48 * 1024 / 4; i += 256) {
        int e = i * 4, row = e >> 10, k4 = e & 1023;
        int grow = (row >> 4) * HID_ + rg * 16 + (row & 15);
        f32x4 v = *(const f32x4*)&Ws[(long)grow * wstride + k4];
        u16x4 o;
        #pragma unroll
        for (int j = 0; j < 4; ++j) o[j] = f2bf(v[j]);
        *(u16x4*)&sA[row * LDS_A_STRIDE + k4] = o;
      }
    } else {
      const unsigned short* Ws = (const unsigned short*)Wsrc;
      for (int i = tid; i < 48 * 1024 / 4; i += 256) {
        int e = i * 4, row = e >> 10, k4 = e & 1023;
        int grow = (row >> 4) * HID_ + rg * 16 + (row & 15);
        *(u16x4*)&sA[row * LDS_A_STRIDE + k4] =
            *(const u16x4*)&Ws[(long)grow * wstride + k4];
      }
    }
  }

  // One-time preloads.
  float bo = 0.f;
  if (isx && tid < 32) bo = ldin(b_out, tid, f32);
  f32x4 bhh[3];
  if (!isx) {
    const int jbase = rg * 16 + jj;
    #pragma unroll
    for (int g = 0; g < 3; ++g)
      #pragma unroll
      for (int t = 0; t < 4; ++t)
        bhh[g][t] = ldin(b_hh, (long)g * HID_ + jbase + t, f32);
  }

  float hreg[4] = {0.f, 0.f, 0.f, 0.f};  // fp32 h master (h-WGs)
  f32x4 sred[3];                          // reduced gh / gix tile rows
  int bar = 0;

  // ---- visibility self-test (probe barrier, bar 0) ----
  if (tid == 0) ast32(&g_vis[wg], (unsigned)wg + 1u);
  gridbar(wg, bar); ++bar;
  if (tid == 0) {
    unsigned p = ((unsigned)wg + 37u) & 255u;
    if (ald32(&g_vis[p]) != p + 1u) store_out(out, f32, wg, 999.0f);  // sentinel
  }

  for (int it = 0; it <= S_; ++it) {
    gridbar(wg, bar); ++bar;   // B1: h_{it-1} limbs + fp32 published

    if (isx && it >= 1) {
      // ---- h-liveness self-test (once) ----
      if (it == 1 && wg == 0 && tid == 0) {
        float s = 0.f;
        for (int i = 0; i < 16; ++i) {
          union { u64_t q; float f[2]; } u; u.q = ald64(&g_hf32[2 * i]);
          s += u.f[0] * u.f[0] + u.f[1] * u.f[1];
        }
        if (s == 0.f) store_out(out, f32, 300, 555.0f);       // sentinel
      }
      // ---- logits + argmax for step it-1, batch b = wg (fp32 h) ----
      // Stage the 4KB h row into LDS once (coherent), then dot from LDS.
      const int b = wg, s = it - 1;
      float* scrp  = sCp;          // 256 fp32 partials
      float* shrow = sCp + 256;    // 8 blocks x 132 (pad) staged h row
      {
        f32x4 hv = ld_f4_coh(&g_hf32[(long)b * HID_ + tid * 4]);
        *(f32x4*)&shrow[(tid >> 5) * 132 + (tid & 31) * 4] = hv;
      }
      __syncthreads();
      {
        int l = tid >> 3, kc = tid & 7;
        const float* hr = shrow + kc * 132;
        float p = 0.f;
        if (f32) {
          const float* wr = (const float*)W_out + (long)l * HID_ + kc * 128;
          for (int k = 0; k < 128; k += 4) {
            f32x4 wa = *(const f32x4*)&wr[k];
            f32x4 ha = *(const f32x4*)&hr[k];
            #pragma unroll
            for (int j = 0; j < 4; ++j) p += wa[j] * ha[j];
          }
        } else {
          const unsigned short* wr =
              (const unsigned short*)W_out + (long)l * HID_ + kc * 128;
          for (int k = 0; k < 128; k += 8) {
            u16x8 w8 = *(const u16x8*)&wr[k];
            f32x4 ha = *(const f32x4*)&hr[k];
            f32x4 hb = *(const f32x4*)&hr[k + 4];
            #pragma unroll
            for (int j = 0; j < 4; ++j) {
              p += bf2f(w8[j]) * ha[j];
              p += bf2f(w8[4 + j]) * hb[j];
            }
          }
        }
        scrp[tid] = p;
      }
      __syncthreads();
      if (tid < 32) {
        const float* pp = sCp + tid * 8;
        float v = pp[0] + pp[1] + pp[2] + pp[3] + pp[4] + pp[5] + pp[6] + pp[7]
                  + bo;
        store_out(out, f32, ((long)b * S_ + s) * NL_ + tid, v);
        float bv = v; int bi = tid;
        #pragma unroll
        for (int off = 16; off; off >>= 1) {
          float v2 = __shfl_down(bv, off, 32);
          int   i2 = __shfl_down(bi, off, 32);
          if (v2 > bv || (v2 == bv && i2 < bi)) { bv = v2; bi = i2; }
        }
        if (tid == 0) asti(&g_pred[b], bi);
      }
      __syncthreads();
    }

    if (it < S_) {
      // ---- 48x64 tile GEMM, K=1024, 4-way K-split, limb passes ----
      f32x4 acc[3][4];
      #pragma unroll
      for (int rt = 0; rt < 3; ++rt)
        #pragma unroll
        for (int bt = 0; bt < 4; ++bt) acc[rt][bt] = f32x4{0.f, 0.f, 0.f, 0.f};

      const int kw0 = wv * 256 + q * 8;

      if (isx) {
        const long bstride = (long)S_ * HID_;
        const long boff = ((long)(bg * 64) * S_ + it) * HID_;
        #pragma unroll
        for (int kb = 0; kb < 8; ++kb) {
          const int k = kw0 + kb * 32;
          short8 avh[3];
          #pragma unroll
          for (int rt = 0; rt < 3; ++rt)
            avh[rt] = ld_bf8(&sA[(rt * 16 + m) * LDS_A_STRIDE + k]);
          if (f32) {
            const float* Bf = (const float*)hs + boff;
            short8 bxh[4], bxl[4];
            #pragma unroll
            for (int bt = 0; bt < 4; ++bt) {
              const float* bp = Bf + (long)(bt * 16 + m) * bstride + k;
              f32x4 x0 = *(const f32x4*)bp;
              f32x4 x1 = *(const f32x4*)(bp + 4);
              u16x8 th, tl;
              #pragma unroll
              for (int j = 0; j < 4; ++j) {
                unsigned short u0 = f2bf(x0[j]);
                th[j] = u0; tl[j] = f2bf(x0[j] - bf2f(u0));
                unsigned short u1 = f2bf(x1[j]);
                th[4 + j] = u1; tl[4 + j] = f2bf(x1[j] - bf2f(u1));
              }
              bxh[bt] = __builtin_bit_cast(short8, th);
              bxl[bt] = __builtin_bit_cast(short8, tl);
            }
            short8 avl[3];
            #pragma unroll
            for (int rt = 0; rt < 3; ++rt)
              avl[rt] = ld_bf8(&g_Wlox[(long)(rt * HID_ + rg * 16 + m) * HID_ + k]);
            #pragma unroll
            for (int rt = 0; rt < 3; ++rt)
              #pragma unroll
              for (int bt = 0; bt < 4; ++bt) {
                acc[rt][bt] = __builtin_amdgcn_mfma_f32_16x16x32_bf16(
                    avh[rt], bxh[bt], acc[rt][bt], 0, 0, 0);
                acc[rt][bt] = __builtin_amdgcn_mfma_f32_16x16x32_bf16(
                    avh[rt], bxl[bt], acc[rt][bt], 0, 0, 0);
                acc[rt][bt] = __builtin_amdgcn_mfma_f32_16x16x32_bf16(
                    avl[rt], bxh[bt], acc[rt][bt], 0, 0, 0);
                acc[rt][bt] = __builtin_amdgcn_mfma_f32_16x16x32_bf16(
                    avl[rt], bxl[bt], acc[rt][bt], 0, 0, 0);
              }
          } else {
            const unsigned short* Bh = (const unsigned short*)hs + boff;
            short8 bxh[4];
            #pragma unroll
            for (int bt = 0; bt < 4; ++bt)
              bxh[bt] = ld_bf8(&Bh[(long)(bt * 16 + m) * bstride + k]);
            #pragma unroll
            for (int rt = 0; rt < 3; ++rt)
              #pragma unroll
              for (int bt = 0; bt < 4; ++bt)
                acc[rt][bt] = __builtin_amdgcn_mfma_f32_16x16x32_bf16(
                    avh[rt], bxh[bt], acc[rt][bt], 0, 0, 0);
          }
        }
      } else {
        const unsigned short* Bhi = g_hhi + (long)(bg * 64) * HID_;
        const unsigned short* Blo = g_hlo + (long)(bg * 64) * HID_;
        #pragma unroll
        for (int kb = 0; kb < 8; ++kb) {
          const int k = kw0 + kb * 32;
          short8 avh[3], bh[4], blv[4];
          #pragma unroll
          for (int rt = 0; rt < 3; ++rt)
            avh[rt] = ld_bf8(&sA[(rt * 16 + m) * LDS_A_STRIDE + k]);
          #pragma unroll
          for (int bt = 0; bt < 4; ++bt) {
            bh[bt]  = ld_bf8_coh(&Bhi[(long)(bt * 16 + m) * HID_ + k]);
            blv[bt] = ld_bf8_coh(&Blo[(long)(bt * 16 + m) * HID_ + k]);
          }
          #pragma unroll
          for (int rt = 0; rt < 3; ++rt)
            #pragma unroll
            for (int bt = 0; bt < 4; ++bt) {
              acc[rt][bt] = __builtin_amdgcn_mfma_f32_16x16x32_bf16(
                  avh[rt], bh[bt], acc[rt][bt], 0, 0, 0);
              acc[rt][bt] = __builtin_amdgcn_mfma_f32_16x16x32_bf16(
                  avh[rt], blv[bt], acc[rt][bt], 0, 0, 0);
            }
          if (f32) {
            short8 avl[3];
            #pragma unroll
            for (int rt = 0; rt < 3; ++rt)
              avl[rt] = ld_bf8(&g_Wlohh[(long)(rt * HID_ + rg * 16 + m) * HID_ + k]);
            #pragma unroll
            for (int rt = 0; rt < 3; ++rt)
              #pragma unroll
              for (int bt = 0; bt < 4; ++bt) {
                acc[rt][bt] = __builtin_amdgcn_mfma_f32_16x16x32_bf16(
                    avl[rt], bh[bt], acc[rt][bt], 0, 0, 0);
                acc[rt][bt] = __builtin_amdgcn_mfma_f32_16x16x32_bf16(
                    avl[rt], blv[bt], acc[rt][bt], 0, 0, 0);
              }
          }
        }
      }

      __syncthreads();  // protect sCp (logits scratch / prior reduction)
      #pragma unroll
      for (int rt = 0; rt < 3; ++rt)
        #pragma unroll
        for (int bt = 0; bt < 4; ++bt)
          *(f32x4*)&sCp[(wv * 64 + bt * 16 + m) * CP_STRIDE + rt * 16 + q * 4] =
              acc[rt][bt];
      __syncthreads();
      #pragma unroll
      for (int g = 0; g < 3; ++g) {
        f32x4 sv = f32x4{0.f, 0.f, 0.f, 0.f};
        #pragma unroll
        for (int w = 0; w < 4; ++w)
          sv += *(const f32x4*)&sCp[(w * 64 + bl) * CP_STRIDE + g * 16 + jj];
        sred[g] = sv;
      }
      if (isx) {
        #pragma unroll
        for (int g = 0; g < 3; ++g)
          st_f4_coh(&g_GIX[((long)slot * 64 + bl) * 48 + g * 16 + jj], sred[g]);
      }
    }

    gridbar(wg, bar); ++bar;   // B2: GIX_it + pred_{it-1} published

    if (!isx && it < S_) {
      // ---- gate epilogue: h_new for (bglob, jbase..jbase+3) ----
      const int bglob = bg * 64 + bl;
      const int jbase = rg * 16 + jj;
      const int pb = aldi(&g_pred[bglob]);
      const float* gl = g_Glab + (long)pb * G3_;
      f32x4 glab[3], gix[3];
      #pragma unroll
      for (int g = 0; g < 3; ++g) {
        glab[g] = *(const f32x4*)&gl[g * HID_ + jbase];
        gix[g]  = ld_f4_coh(&g_GIX[((long)slot * 64 + bl) * 48 + g * 16 + jj]);
      }
      u16x4 whi, wlo;
      f32x4 hf;
      #pragma unroll
      for (int t4 = 0; t4 < 4; ++t4) {
        float ghr = sred[0][t4] + bhh[0][t4];
        float ghz = sred[1][t4] + bhh[1][t4];
        float ghn = sred[2][t4] + bhh[2][t4];
        float gir = gix[0][t4] + glab[0][t4];   // b_ih folded into G_lab
        float giz = gix[1][t4] + glab[1][t4];
        float gin = gix[2][t4] + glab[2][t4];
        float r = 1.f / (1.f + expf(-(gir + ghr)));
        float z = 1.f / (1.f + expf(-(giz + ghz)));
        float n = tanhf(gin + r * ghn);   // b_hh_n inside r*(...) per PyTorch
        float hn = (1.f - z) * n + z * hreg[t4];
        hreg[t4] = hn;
        hf[t4] = hn;
        unsigned short uhi = f2bf(hn);
        whi[t4] = uhi;
        wlo[t4] = f2bf(hn - bf2f(uhi));
      }
      st_h4_coh(&g_hhi[(long)bglob * HID_ + jbase], whi);
      st_h4_coh(&g_hlo[(long)bglob * HID_ + jbase], wlo);
      st_f4_coh(&g_hf32[(long)bglob * HID_ + jbase], hf);
    }
  }
}

extern "C" void kernel_launch(void* const* d_in, const int* in_sizes, int n_in,
                              void* d_out, int out_size, void* d_ws, size_t ws_size,
                              hipStream_t stream) {
  const void* hs    = d_in[0];
  const void* emb   = d_in[1];
  const void* W_ih  = d_in[2];
  const void* W_hh  = d_in[3];
  const void* b_ih  = d_in[4];
  const void* b_hh  = d_in[5];
  const void* W_out = d_in[6];
  const void* b_out = d_in[7];

  hipLaunchKernelGGL(k_zero, dim3(256), dim3(256), 0, stream);
  hipLaunchKernelGGL(k_detect, dim3(1), dim3(64), 0, stream,
                     (const unsigned short*)W_ih);
  hipLaunchKernelGGL(k_prep, dim3(32 * 12), dim3(256), 0, stream,
                     emb, W_ih, b_ih);
  hipLaunchKernelGGL(k_prepw, dim3(3072), dim3(256), 0, stream, W_ih, W_hh);
  hipFuncSetAttribute((const void*)k_seq,
                      hipFuncAttributeMaxDynamicSharedMemorySize, LDS_BYTES);
  hipLaunchKernelGGL(k_seq, dim3(256), dim3(256), LDS_BYTES, stream,
                     hs, W_ih, W_hh, b_hh, W_out, b_out, d_out);
}